// Round 5
// baseline (594.052 us; speedup 1.0000x reference)
//
#include <hip/hip_runtime.h>
#include <stdint.h>

#define TT 4096    // B*S tokens
#define DD 1024    // model dim
#define EE 8       // experts
#define HH 1792    // hidden dim
#define MP 10240   // max padded gathered rows (40*256)
#define MT256 40   // max 256-row tiles

typedef __attribute__((ext_vector_type(8))) short short8;    // 8 x bf16
typedef __attribute__((ext_vector_type(4))) short short4v;   // 4 x bf16
typedef __attribute__((ext_vector_type(4))) float f32x4;

static __device__ __forceinline__ unsigned short f2bf(float f) {
  union { float f; uint32_t u; } v; v.f = f;
  return (unsigned short)((v.u + 0x7fffu + ((v.u >> 16) & 1u)) >> 16);  // RNE
}
static __device__ __forceinline__ float bf2f(unsigned short h) {
  union { uint32_t u; float f; } v; v.u = ((uint32_t)h) << 16;
  return v.f;
}

// async global->LDS, 16B/lane; LDS dest wave-uniform (HW adds lane*16)
static __device__ __forceinline__ void gll16(const void* g, const void* l) {
  __builtin_amdgcn_global_load_lds(
      (const __attribute__((address_space(1))) unsigned int*)g,
      (__attribute__((address_space(3))) unsigned int*)l, 16, 0, 0);
}

// ---------------- weight transpose+convert: f32 [R][C] -> bf16 [C][R] ----------------
// ilv=1: dst row for source col c is (c>>4)*32 + sel*16 + (c&15)  (G/U 16-col interleave)
__global__ __launch_bounds__(256) void transpose_convert(
    const float* __restrict__ in, unsigned short* __restrict__ outp, int R, int C,
    int ilv, int sel) {
  __shared__ float t[64][68];
  const float* src = in + (size_t)blockIdx.z * R * C + (size_t)(blockIdx.x * 64) * C +
                     blockIdx.y * 64;
  unsigned short* dst = outp + (size_t)blockIdx.z * R * C * (ilv ? 2 : 1);
  const int tid = threadIdx.x;
  const int lr = tid >> 2, lc = (tid & 3) * 16;
#pragma unroll
  for (int q = 0; q < 4; ++q) {
    const f32x4 v = *(const f32x4*)(src + (size_t)lr * C + lc + 4 * q);
    t[lr][lc + 4 * q + 0] = v[0]; t[lr][lc + 4 * q + 1] = v[1];
    t[lr][lc + 4 * q + 2] = v[2]; t[lr][lc + 4 * q + 3] = v[3];
  }
  __syncthreads();
  unsigned short b[16];
#pragma unroll
  for (int q = 0; q < 16; ++q) b[q] = f2bf(t[lc + q][lr]);
  const int cg = blockIdx.y * 64 + lr;                       // source col (dst logical row)
  const int prow = ilv ? ((cg >> 4) * 32 + sel * 16 + (cg & 15)) : cg;
  unsigned short* d = dst + (size_t)prow * R + blockIdx.x * 64 + lc;
  *(short8*)(d) = *(const short8*)&b[0];
  *(short8*)(d + 8) = *(const short8*)&b[8];
}

// ---------------- gate: logits (bf16-emulated), top-2, combine, probs, topk ----------------
__global__ __launch_bounds__(256) void gate_kernel(
    const float* __restrict__ x, const float* __restrict__ gw,
    float* __restrict__ combine, float* __restrict__ probs, int2* __restrict__ topk) {
  const int lane = threadIdx.x & 63;
  const int wave = threadIdx.x >> 6;
  const int t = blockIdx.x * 4 + wave;
  const float* xr = x + (size_t)t * DD;
  float acc[EE];
#pragma unroll
  for (int e = 0; e < EE; ++e) acc[e] = 0.f;
  for (int i = 0; i < DD / 64; ++i) {
    const int d = i * 64 + lane;
    const float xv = bf2f(f2bf(xr[d]));
#pragma unroll
    for (int e = 0; e < EE; ++e)
      acc[e] += xv * bf2f(f2bf(gw[e * DD + d]));
  }
#pragma unroll
  for (int e = 0; e < EE; ++e) {
#pragma unroll
    for (int off = 32; off > 0; off >>= 1)
      acc[e] += __shfl_xor(acc[e], off, 64);
  }
  if (lane == 0) {
    float lg[EE];
#pragma unroll
    for (int e = 0; e < EE; ++e) lg[e] = bf2f(f2bf(acc[e]));
    float m1 = -1e30f, m2 = -1e30f; int i1 = 0, i2 = 0;
#pragma unroll
    for (int e = 0; e < EE; ++e) {
      const float v = lg[e];
      if (v > m1) { m2 = m1; i2 = i1; m1 = v; i1 = e; }
      else if (v > m2) { m2 = v; i2 = e; }
    }
    const float e2 = expf(m2 - m1);
    const float w1 = 1.f / (1.f + e2);
    const float w2 = e2 * w1;
    float cb[EE];
#pragma unroll
    for (int e = 0; e < EE; ++e) cb[e] = 0.f;
    cb[i1] = w1; cb[i2] += w2;
    float p[EE]; float s = 0.f;
#pragma unroll
    for (int e = 0; e < EE; ++e) { p[e] = expf(lg[e] - m1); s += p[e]; }
    const float inv = 1.f / s;
#pragma unroll
    for (int e = 0; e < EE; ++e) {
      combine[(size_t)t * EE + e] = cb[e];
      probs[(size_t)t * EE + e] = p[e] * inv;
    }
    topk[t] = make_int2(i1, i2);
  }
}

// ---------------- deterministic probs reduction -> mean_probs + loss ----------------
__global__ __launch_bounds__(256) void reduce_kernel(
    const float* __restrict__ probs, float* __restrict__ tail) {
  const int tid = threadIdx.x;
  const int lane = tid & 63, wave = tid >> 6;
  float acc[EE];
#pragma unroll
  for (int e = 0; e < EE; ++e) acc[e] = 0.f;
  for (int t = tid; t < TT; t += 256) {
#pragma unroll
    for (int e = 0; e < EE; ++e) acc[e] += probs[(size_t)t * EE + e];
  }
#pragma unroll
  for (int e = 0; e < EE; ++e) {
#pragma unroll
    for (int off = 32; off > 0; off >>= 1)
      acc[e] += __shfl_xor(acc[e], off, 64);
  }
  __shared__ float sm[4][EE];
  if (lane == 0) {
#pragma unroll
    for (int e = 0; e < EE; ++e) sm[wave][e] = acc[e];
  }
  __syncthreads();
  if (tid == 0) {
    float loss = 0.f;
#pragma unroll
    for (int e = 0; e < EE; ++e) {
      const float m = (sm[0][e] + sm[1][e] + sm[2][e] + sm[3][e]) * (1.f / TT);
      tail[1 + e] = m;
      loss += m * m;
    }
    tail[0] = (float)EE * loss;
  }
}

// ---------------- routing: compacted token lists (pad to 256) + tile table ----------------
__global__ __launch_bounds__(512) void route_kernel(
    const int2* __restrict__ topk, const float* __restrict__ combine,
    int* __restrict__ tok_list, float* __restrict__ wt_list, int* __restrict__ tab256) {
  const int lane = threadIdx.x & 63;
  const int e = threadIdx.x >> 6;  // one wave per expert
  __shared__ int cnts[EE], offs[EE];
  int cnt = 0;
  for (int i = 0; i < TT / 64; ++i) {
    const int2 k2 = topk[i * 64 + lane];
    cnt += __popcll(__ballot(k2.x == e || k2.y == e));
  }
  if (lane == 0) cnts[e] = cnt;
  __syncthreads();
  if (threadIdx.x == 0) {
    int off = 0, n256 = 0;
    for (int f = 0; f < EE; ++f) {
      offs[f] = off;
      const int pc = (cnts[f] + 255) & ~255;
      for (int j = 0; j < (pc >> 8); ++j) {
        tab256[2 * n256] = f; tab256[2 * n256 + 1] = off + 256 * j; ++n256;
      }
      off += pc;
    }
    for (; n256 < MT256; ++n256) { tab256[2 * n256] = -1; tab256[2 * n256 + 1] = 0; }
  }
  __syncthreads();
  int pos = offs[e];
  for (int i = 0; i < TT / 64; ++i) {
    const int t = i * 64 + lane;
    const int2 k2 = topk[t];
    const bool sel = (k2.x == e || k2.y == e);
    const unsigned long long m = __ballot(sel);
    if (sel) {
      const int p = pos + __popcll(m & ((1ull << lane) - 1ull));
      tok_list[p] = t;
      wt_list[p] = combine[(size_t)t * EE + e];
    }
    pos += __popcll(m);
  }
  const int pc = (cnt + 255) & ~255;  // pad slots: token 0, weight 0
  for (int s = cnt + lane; s < pc; s += 64) {
    tok_list[offs[e] + s] = 0;
    wt_list[offs[e] + s] = 0.f;
  }
}

// ---------------- gather x rows (f32 -> bf16) into contiguous padded buffer ----------------
__global__ __launch_bounds__(256) void gather_x(
    const float* __restrict__ x, const int* __restrict__ tok_list,
    const int* __restrict__ tab256, unsigned short* __restrict__ xg) {
  const int e = tab256[2 * blockIdx.x];
  if (e < 0) return;
  const int row0 = tab256[2 * blockIdx.x + 1] + blockIdx.y * 16;
  const int tid = threadIdx.x;
#pragma unroll
  for (int i = 0; i < 16; ++i) {
    const int row = row0 + i;
    const int tok = tok_list[row];
    const f32x4 v = *(const f32x4*)(x + (size_t)tok * DD + tid * 4);
    unsigned short b[4] = {f2bf(v[0]), f2bf(v[1]), f2bf(v[2]), f2bf(v[3])};
    *(short4v*)(xg + (size_t)row * DD + tid * 4) = *(const short4v*)b;
  }
}

// ---------------- grouped GEMM: dbuf-2 K64 tiles, 4-phase/K-tile, 2-tile parity unroll ----
// MODE 0: BM=256 BN=256, A=xg [row][DD], B=wguT interleaved; epilogue silu(g)*u -> act bf16
// MODE 1: BM=256 BN=128, A=act [row][HH], B=wdT; epilogue atomic scatter * combine wt
// LDS rows are 128B; swizzle: phys 16B-chunk = logical ^ (row&7), both-sides.
// Stage order per tile t (1 half/phase into buf of t+1): ph1:Blo ph2:Bhi ph3:Alo ph4:Ahi
//   (mode1: ph1:B ph2:Alo ph3:Ahi ph4:-)
// Counted vmcnt: ph1 waits vmcnt(2) [retires A(t) halves, read in ph2/ph3];
//                ph4 waits vmcnt(4) [retires B(t+1) halves, read in ph1(t+1)].
#define PH_SYNC(VC)                                         \
  __builtin_amdgcn_sched_barrier(0);                        \
  asm volatile("s_waitcnt vmcnt(" #VC ")" ::: "memory");    \
  __builtin_amdgcn_s_barrier();                             \
  asm volatile("s_waitcnt lgkmcnt(0)" ::: "memory");        \
  __builtin_amdgcn_sched_barrier(0);
#define PH_SYNCN                                            \
  __builtin_amdgcn_sched_barrier(0);                        \
  __builtin_amdgcn_s_barrier();                             \
  asm volatile("s_waitcnt lgkmcnt(0)" ::: "memory");        \
  __builtin_amdgcn_sched_barrier(0);
#define PH_END                                              \
  __builtin_amdgcn_sched_barrier(0);                        \
  __builtin_amdgcn_s_barrier();

template <int MODE>
__global__ __launch_bounds__(512, 1) void gemm_main(
    const unsigned short* __restrict__ Ab, const unsigned short* __restrict__ Bb,
    const int* __restrict__ tab, const int* __restrict__ tok_list,
    const float* __restrict__ wt_list, unsigned short* __restrict__ act,
    float* __restrict__ out) {
  constexpr int K    = (MODE == 0) ? DD : HH;    // 1024 / 1792
  constexpr int NK   = K / 64;                   // 16 / 28 K-tiles (even)
  constexpr int BN   = (MODE == 0) ? 256 : 128;
  constexpr int NBR  = (MODE == 0) ? 2 * HH : DD;
  constexpr int NNT  = NBR / BN;                 // 14 / 8
  constexpr int ABYT = 256 * 128;                // 32KB A per buf
  constexpr int BUFB = ABYT + BN * 128;          // 64KB / 48KB
  extern __shared__ char lds[];

  const int nwg = gridDim.x;  // %8==0 for both modes
  const int wgid = (blockIdx.x & 7) * (nwg >> 3) + (blockIdx.x >> 3);
  const int mt = wgid / NNT, nt = wgid % NNT;
  const int e = tab[2 * mt];
  if (e < 0) return;
  const int row0 = tab[2 * mt + 1];
  const int n0 = nt * BN;

  const int tid = threadIdx.x, lane = tid & 63, wave = tid >> 6;
  const int wm = (MODE == 0) ? (wave >> 2) * 128 : (wave >> 1) * 64;
  const int wn = (MODE == 0) ? (wave & 3) * 64 : (wave & 1) * 64;
  const int fr = lane & 15, hi = lane >> 4;

  const unsigned short* At = Ab + (size_t)row0 * K;
  const unsigned short* Bt = Bb + ((size_t)e * NBR + n0) * K;

  asm volatile("s_waitcnt vmcnt(0)" ::: "memory");  // exact vmem accounting below

  // stage half h (0=Alo rows0-127, 1=Ahi, 2=Blo, 3=Bhi) of tile u into buf p
  auto stage_half = [&](int u, int p, int h) {
    const bool isA = (h < 2);
    const unsigned short* src = isA ? At : Bt;
    const int rbase = (h & 1) * 128;
    const int lbase = p * BUFB + (isA ? 0 : ABYT) + rbase * 128;
#pragma unroll
    for (int q = 0; q < 2; ++q) {
      const int rel = q * 8192 + wave * 1024 + lane * 16;
      const int row = rel >> 7, ch = (rel >> 4) & 7;
      gll16(src + (size_t)(rbase + row) * K + u * 64 + ((ch ^ (row & 7)) << 3),
            lds + lbase + q * 8192 + wave * 1024);
    }
  };
  auto rdA = [&](int p, int row, int kc) -> short8 {
    const int lb = row * 128 + kc * 64 + hi * 16;
    return *(const short8*)(lds + p * BUFB + (lb ^ ((row & 7) << 4)));
  };
  auto rdB = [&](int p, int row, int kc) -> short8 {
    const int lb = row * 128 + kc * 64 + hi * 16;
    return *(const short8*)(lds + p * BUFB + ABYT + (lb ^ ((row & 7) << 4)));
  };

  constexpr int NIT = (MODE == 0) ? 8 : 4;
  f32x4 acc[NIT][4];
#pragma unroll
  for (int i = 0; i < NIT; ++i)
#pragma unroll
    for (int j = 0; j < 4; ++j) acc[i][j] = (f32x4){0.f, 0.f, 0.f, 0.f};

  // prologue: tile 0 fully staged into buf 0, full drain
  if constexpr (MODE == 0) { stage_half(0, 0, 2); stage_half(0, 0, 3); }
  else                     { stage_half(0, 0, 2); }
  stage_half(0, 0, 0); stage_half(0, 0, 1);
  asm volatile("s_waitcnt vmcnt(0)" ::: "memory");
  __builtin_amdgcn_s_barrier();

  if constexpr (MODE == 0) {
    short8 rB[2][4][2], rA03[4][2], rA47[2][4][2];
#pragma unroll 1
    for (int tt = 0; tt < NK; tt += 2) {
#pragma unroll
      for (int par = 0; par < 2; ++par) {
        const int t = tt + par;
        const int p = par, pn = par ^ 1;
        const int u = (t + 1 < NK) ? t + 1 : 0;
        // ph1: read B(t)[8]; stage Blo(t+1); MFMA Q(m-hi, n-lo)(t-1)
#pragma unroll
        for (int j = 0; j < 4; ++j)
#pragma unroll
          for (int kc = 0; kc < 2; ++kc) rB[p][j][kc] = rdB(p, wn + j * 16 + fr, kc);
        stage_half(u, pn, 2);
        PH_SYNC(2)
        if (t > 0) {
          __builtin_amdgcn_s_setprio(1);
#pragma unroll
          for (int i = 0; i < 4; ++i)
#pragma unroll
            for (int j = 0; j < 2; ++j)
#pragma unroll
              for (int kc = 0; kc < 2; ++kc)
                acc[4 + i][j] = __builtin_amdgcn_mfma_f32_16x16x32_bf16(
                    rA47[pn][i][kc], rB[pn][j][kc], acc[4 + i][j], 0, 0, 0);
          __builtin_amdgcn_s_setprio(0);
        }
        PH_END
        // ph2: read A03(t)[8]; stage Bhi(t+1); MFMA Q(m-hi, n-hi)(t-1)
#pragma unroll
        for (int i = 0; i < 4; ++i)
#pragma unroll
          for (int kc = 0; kc < 2; ++kc) rA03[i][kc] = rdA(p, wm + i * 16 + fr, kc);
        stage_half(u, pn, 3);
        PH_SYNCN
        if (t > 0) {
          __builtin_amdgcn_s_setprio(1);
#pragma unroll
          for (int i = 0; i < 4; ++i)
#pragma unroll
            for (int j = 0; j < 2; ++j)
#pragma unroll
              for (int kc = 0; kc < 2; ++kc)
                acc[4 + i][2 + j] = __builtin_amdgcn_mfma_f32_16x16x32_bf16(
                    rA47[pn][i][kc], rB[pn][2 + j][kc], acc[4 + i][2 + j], 0, 0, 0);
          __builtin_amdgcn_s_setprio(0);
        }
        PH_END
        // ph3: read A47(t)[8]; stage Alo(t+1); MFMA Q(m-lo, n-lo)(t)
#pragma unroll
        for (int i = 0; i < 4; ++i)
#pragma unroll
          for (int kc = 0; kc < 2; ++kc) rA47[p][i][kc] = rdA(p, wm + 64 + i * 16 + fr, kc);
        stage_half(u, pn, 0);
        PH_SYNCN
        __builtin_amdgcn_s_setprio(1);
#pragma unroll
        for (int i = 0; i < 4; ++i)
#pragma unroll
          for (int j = 0; j < 2; ++j)
#pragma unroll
            for (int kc = 0; kc < 2; ++kc)
              acc[i][j] = __builtin_amdgcn_mfma_f32_16x16x32_bf16(
                  rA03[i][kc], rB[p][j][kc], acc[i][j], 0, 0, 0);
        __builtin_amdgcn_s_setprio(0);
        PH_END
        // ph4: stage Ahi(t+1); vmcnt(4); MFMA Q(m-lo, n-hi)(t)
        stage_half(u, pn, 1);
        PH_SYNC(4)
        __builtin_amdgcn_s_setprio(1);
#pragma unroll
        for (int i = 0; i < 4; ++i)
#pragma unroll
          for (int j = 0; j < 2; ++j)
#pragma unroll
            for (int kc = 0; kc < 2; ++kc)
              acc[i][2 + j] = __builtin_amdgcn_mfma_f32_16x16x32_bf16(
                  rA03[i][kc], rB[p][2 + j][kc], acc[i][2 + j], 0, 0, 0);
        __builtin_amdgcn_s_setprio(0);
        PH_END
      }
    }
    // epilogue MFMA: Q(m-hi, *) of tile NK-1 (parity 1)
#pragma unroll
    for (int i = 0; i < 4; ++i)
#pragma unroll
      for (int j = 0; j < 4; ++j)
#pragma unroll
        for (int kc = 0; kc < 2; ++kc)
          acc[4 + i][j] = __builtin_amdgcn_mfma_f32_16x16x32_bf16(
              rA47[1][i][kc], rB[1][j][kc], acc[4 + i][j], 0, 0, 0);
  } else {
    short8 rB[2][4][2], rA01[2][2], rA23[2][2][2];
#pragma unroll 1
    for (int tt = 0; tt < NK; tt += 2) {
#pragma unroll
      for (int par = 0; par < 2; ++par) {
        const int t = tt + par;
        const int p = par, pn = par ^ 1;
        const int u = (t + 1 < NK) ? t + 1 : 0;
        // ph1: read B(t)[8]; stage B(t+1); MFMA Q(m23, n01)(t-1)
#pragma unroll
        for (int j = 0; j < 4; ++j)
#pragma unroll
          for (int kc = 0; kc < 2; ++kc) rB[p][j][kc] = rdB(p, wn + j * 16 + fr, kc);
        stage_half(u, pn, 2);
        PH_SYNC(2)
        if (t > 0) {
          __builtin_amdgcn_s_setprio(1);
#pragma unroll
          for (int i = 0; i < 2; ++i)
#pragma unroll
            for (int j = 0; j < 2; ++j)
#pragma unroll
              for (int kc = 0; kc < 2; ++kc)
                acc[2 + i][j] = __builtin_amdgcn_mfma_f32_16x16x32_bf16(
                    rA23[pn][i][kc], rB[pn][j][kc], acc[2 + i][j], 0, 0, 0);
          __builtin_amdgcn_s_setprio(0);
        }
        PH_END
        // ph2: read A(t)[8]; stage Alo(t+1); MFMA Q(m23, n23)(t-1)
#pragma unroll
        for (int i = 0; i < 2; ++i)
#pragma unroll
          for (int kc = 0; kc < 2; ++kc) {
            rA01[i][kc] = rdA(p, wm + i * 16 + fr, kc);
            rA23[p][i][kc] = rdA(p, wm + 32 + i * 16 + fr, kc);
          }
        stage_half(u, pn, 0);
        PH_SYNCN
        if (t > 0) {
          __builtin_amdgcn_s_setprio(1);
#pragma unroll
          for (int i = 0; i < 2; ++i)
#pragma unroll
            for (int j = 0; j < 2; ++j)
#pragma unroll
              for (int kc = 0; kc < 2; ++kc)
                acc[2 + i][2 + j] = __builtin_amdgcn_mfma_f32_16x16x32_bf16(
                    rA23[pn][i][kc], rB[pn][2 + j][kc], acc[2 + i][2 + j], 0, 0, 0);
          __builtin_amdgcn_s_setprio(0);
        }
        PH_END
        // ph3: stage Ahi(t+1); MFMA Q(m01, n01)(t)
        stage_half(u, pn, 1);
        PH_SYNCN
        __builtin_amdgcn_s_setprio(1);
#pragma unroll
        for (int i = 0; i < 2; ++i)
#pragma unroll
          for (int j = 0; j < 2; ++j)
#pragma unroll
            for (int kc = 0; kc < 2; ++kc)
              acc[i][j] = __builtin_amdgcn_mfma_f32_16x16x32_bf16(
                  rA01[i][kc], rB[p][j][kc], acc[i][j], 0, 0, 0);
        __builtin_amdgcn_s_setprio(0);
        PH_END
        // ph4: vmcnt(4); MFMA Q(m01, n23)(t)
        PH_SYNC(4)
        __builtin_amdgcn_s_setprio(1);
#pragma unroll
        for (int i = 0; i < 2; ++i)
#pragma unroll
          for (int j = 0; j < 2; ++j)
#pragma unroll
            for (int kc = 0; kc < 2; ++kc)
              acc[i][2 + j] = __builtin_amdgcn_mfma_f32_16x16x32_bf16(
                  rA01[i][kc], rB[p][2 + j][kc], acc[i][2 + j], 0, 0, 0);
        __builtin_amdgcn_s_setprio(0);
        PH_END
      }
    }
    // epilogue MFMA: Q(m23, *) of tile NK-1 (parity 1)
#pragma unroll
    for (int i = 0; i < 2; ++i)
#pragma unroll
      for (int j = 0; j < 4; ++j)
#pragma unroll
        for (int kc = 0; kc < 2; ++kc)
          acc[2 + i][j] = __builtin_amdgcn_mfma_f32_16x16x32_bf16(
              rA23[1][i][kc], rB[1][j][kc], acc[2 + i][j], 0, 0, 0);
  }
  asm volatile("s_waitcnt vmcnt(0)" ::: "memory");

  const int r4 = hi * 4;
  if constexpr (MODE == 0) {
#pragma unroll
    for (int i = 0; i < NIT; ++i)
#pragma unroll
      for (int r = 0; r < 4; ++r) {
        const int row = row0 + wm + i * 16 + r4 + r;
#pragma unroll
        for (int jj = 0; jj < 2; ++jj) {
          const float g = acc[i][2 * jj][r], u = acc[i][2 * jj + 1][r];
          const int nb = n0 + wn + jj * 32;
          const int h = ((nb >> 5) << 4) + fr;   // de-interleave to real H col
          act[(size_t)row * HH + h] = f2bf((g / (1.f + expf(-g))) * u);
        }
      }
  } else {
#pragma unroll
    for (int i = 0; i < NIT; ++i)
#pragma unroll
      for (int r = 0; r < 4; ++r) {
        const int rl = row0 + wm + i * 16 + r4 + r;
        const int tok = tok_list[rl];
        const float wt = wt_list[rl];
        if (wt != 0.f) {
#pragma unroll
          for (int j = 0; j < 4; ++j)
            unsafeAtomicAdd(&out[(size_t)tok * DD + n0 + wn + j * 16 + fr],
                            acc[i][j][r] * wt);
        }
      }
  }
}

extern "C" void kernel_launch(void* const* d_in, const int* in_sizes, int n_in,
                              void* d_out, int out_size, void* d_ws, size_t ws_size,
                              hipStream_t stream) {
  const float* x      = (const float*)d_in[0];
  const float* gw     = (const float*)d_in[1];
  const float* w_gate = (const float*)d_in[2];
  const float* w_up   = (const float*)d_in[3];
  const float* w_down = (const float*)d_in[4];
  float* out = (float*)d_out;
  float* tail = out + (size_t)TT * DD;  // [loss, mean_probs x 8]

  char* w = (char*)d_ws;
  size_t o = 0;
  auto carve = [&](size_t bytes) { char* p = w + o; o += (bytes + 255) & ~255ull; return p; };
  unsigned short* wguT = (unsigned short*)carve((size_t)EE * 2 * HH * DD * 2);  // interleaved G/U
  unsigned short* wdT  = (unsigned short*)carve((size_t)EE * DD * HH * 2);
  unsigned short* xg   = (unsigned short*)carve((size_t)MP * DD * 2);
  unsigned short* act  = (unsigned short*)carve((size_t)MP * HH * 2);
  float* combine = (float*)carve((size_t)TT * EE * 4);
  float* probs   = (float*)carve((size_t)TT * EE * 4);
  int2* topk     = (int2*)carve((size_t)TT * 8);
  int* tok_list  = (int*)carve((size_t)MP * 4);
  float* wt_list = (float*)carve((size_t)MP * 4);
  int* tab256    = (int*)carve((size_t)MT256 * 8);

  hipMemsetAsync(out, 0, (size_t)TT * DD * sizeof(float), stream);

  transpose_convert<<<dim3(DD / 64, HH / 64, EE), 256, 0, stream>>>(w_gate, wguT, DD, HH, 1, 0);
  transpose_convert<<<dim3(DD / 64, HH / 64, EE), 256, 0, stream>>>(w_up,   wguT, DD, HH, 1, 1);
  transpose_convert<<<dim3(HH / 64, DD / 64, EE), 256, 0, stream>>>(w_down, wdT,  HH, DD, 0, 0);

  gate_kernel<<<TT / 4, 256, 0, stream>>>(x, gw, combine, probs, topk);
  reduce_kernel<<<1, 256, 0, stream>>>(probs, tail);
  route_kernel<<<1, 512, 0, stream>>>(topk, combine, tok_list, wt_list, tab256);
  gather_x<<<dim3(MT256, 16), 256, 0, stream>>>(x, tok_list, tab256, xg);

  hipFuncSetAttribute(reinterpret_cast<const void*>(&gemm_main<0>),
                      hipFuncAttributeMaxDynamicSharedMemorySize, 131072);
  hipFuncSetAttribute(reinterpret_cast<const void*>(&gemm_main<1>),
                      hipFuncAttributeMaxDynamicSharedMemorySize, 98304);

  gemm_main<0><<<MT256 * 14, 512, 131072, stream>>>(xg, wguT, tab256, nullptr, nullptr, act, nullptr);
  gemm_main<1><<<MT256 * 8, 512, 98304, stream>>>(act, wdT, tab256, tok_list, wt_list, nullptr, out);
}

// Round 7
// 273.114 us; speedup vs baseline: 2.1751x; 2.1751x over previous
//
#include <hip/hip_runtime.h>
#include <stdint.h>

#define TT 4096    // B*S tokens
#define DD 1024    // model dim
#define EE 8       // experts
#define HH 1792    // hidden dim
#define MP 10240   // max padded gathered rows (40*256)
#define MT256 40   // max 256-row tiles
#define MT128 80   // max 128-row tiles

typedef __attribute__((ext_vector_type(8))) short short8;    // 8 x bf16
typedef __attribute__((ext_vector_type(4))) short short4v;   // 4 x bf16
typedef __attribute__((ext_vector_type(4))) float f32x4;

static __device__ __forceinline__ unsigned short f2bf(float f) {
  union { float f; uint32_t u; } v; v.f = f;
  return (unsigned short)((v.u + 0x7fffu + ((v.u >> 16) & 1u)) >> 16);  // RNE
}
static __device__ __forceinline__ float bf2f(unsigned short h) {
  union { uint32_t u; float f; } v; v.u = ((uint32_t)h) << 16;
  return v.f;
}

// async global->LDS, 16B/lane; LDS dest wave-uniform (HW adds lane*16)
static __device__ __forceinline__ void gll16(const void* g, const void* l) {
  __builtin_amdgcn_global_load_lds(
      (const __attribute__((address_space(1))) unsigned int*)g,
      (__attribute__((address_space(3))) unsigned int*)l, 16, 0, 0);
}

// ---------------- weight transpose+convert: f32 [R][C] -> bf16 [C][R] ----------------
// ilv=1: dst row for source col c is (c>>4)*32 + sel*16 + (c&15)  (G/U 16-col interleave)
__global__ __launch_bounds__(256) void transpose_convert(
    const float* __restrict__ in, unsigned short* __restrict__ outp, int R, int C,
    int ilv, int sel) {
  __shared__ float t[64][68];
  const float* src = in + (size_t)blockIdx.z * R * C + (size_t)(blockIdx.x * 64) * C +
                     blockIdx.y * 64;
  unsigned short* dst = outp + (size_t)blockIdx.z * R * C * (ilv ? 2 : 1);
  const int tid = threadIdx.x;
  const int lr = tid >> 2, lc = (tid & 3) * 16;
#pragma unroll
  for (int q = 0; q < 4; ++q) {
    const f32x4 v = *(const f32x4*)(src + (size_t)lr * C + lc + 4 * q);
    t[lr][lc + 4 * q + 0] = v[0]; t[lr][lc + 4 * q + 1] = v[1];
    t[lr][lc + 4 * q + 2] = v[2]; t[lr][lc + 4 * q + 3] = v[3];
  }
  __syncthreads();
  unsigned short b[16];
#pragma unroll
  for (int q = 0; q < 16; ++q) b[q] = f2bf(t[lc + q][lr]);
  const int cg = blockIdx.y * 64 + lr;                       // source col (dst logical row)
  const int prow = ilv ? ((cg >> 4) * 32 + sel * 16 + (cg & 15)) : cg;
  unsigned short* d = dst + (size_t)prow * R + blockIdx.x * 64 + lc;
  *(short8*)(d) = *(const short8*)&b[0];
  *(short8*)(d + 8) = *(const short8*)&b[8];
}

// ---------------- gate: logits (bf16-emulated), top-2, combine, probs, topk ----------------
__global__ __launch_bounds__(256) void gate_kernel(
    const float* __restrict__ x, const float* __restrict__ gw,
    float* __restrict__ combine, float* __restrict__ probs, int2* __restrict__ topk) {
  const int lane = threadIdx.x & 63;
  const int wave = threadIdx.x >> 6;
  const int t = blockIdx.x * 4 + wave;
  const float* xr = x + (size_t)t * DD;
  float acc[EE];
#pragma unroll
  for (int e = 0; e < EE; ++e) acc[e] = 0.f;
  for (int i = 0; i < DD / 64; ++i) {
    const int d = i * 64 + lane;
    const float xv = bf2f(f2bf(xr[d]));
#pragma unroll
    for (int e = 0; e < EE; ++e)
      acc[e] += xv * bf2f(f2bf(gw[e * DD + d]));
  }
#pragma unroll
  for (int e = 0; e < EE; ++e) {
#pragma unroll
    for (int off = 32; off > 0; off >>= 1)
      acc[e] += __shfl_xor(acc[e], off, 64);
  }
  if (lane == 0) {
    float lg[EE];
#pragma unroll
    for (int e = 0; e < EE; ++e) lg[e] = bf2f(f2bf(acc[e]));
    float m1 = -1e30f, m2 = -1e30f; int i1 = 0, i2 = 0;
#pragma unroll
    for (int e = 0; e < EE; ++e) {
      const float v = lg[e];
      if (v > m1) { m2 = m1; i2 = i1; m1 = v; i1 = e; }
      else if (v > m2) { m2 = v; i2 = e; }
    }
    const float e2 = expf(m2 - m1);
    const float w1 = 1.f / (1.f + e2);
    const float w2 = e2 * w1;
    float cb[EE];
#pragma unroll
    for (int e = 0; e < EE; ++e) cb[e] = 0.f;
    cb[i1] = w1; cb[i2] += w2;
    float p[EE]; float s = 0.f;
#pragma unroll
    for (int e = 0; e < EE; ++e) { p[e] = expf(lg[e] - m1); s += p[e]; }
    const float inv = 1.f / s;
#pragma unroll
    for (int e = 0; e < EE; ++e) {
      combine[(size_t)t * EE + e] = cb[e];
      probs[(size_t)t * EE + e] = p[e] * inv;
    }
    topk[t] = make_int2(i1, i2);
  }
}

// ---------------- deterministic probs reduction -> mean_probs + loss ----------------
__global__ __launch_bounds__(256) void reduce_kernel(
    const float* __restrict__ probs, float* __restrict__ tail) {
  const int tid = threadIdx.x;
  const int lane = tid & 63, wave = tid >> 6;
  float acc[EE];
#pragma unroll
  for (int e = 0; e < EE; ++e) acc[e] = 0.f;
  for (int t = tid; t < TT; t += 256) {
#pragma unroll
    for (int e = 0; e < EE; ++e) acc[e] += probs[(size_t)t * EE + e];
  }
#pragma unroll
  for (int e = 0; e < EE; ++e) {
#pragma unroll
    for (int off = 32; off > 0; off >>= 1)
      acc[e] += __shfl_xor(acc[e], off, 64);
  }
  __shared__ float sm[4][EE];
  if (lane == 0) {
#pragma unroll
    for (int e = 0; e < EE; ++e) sm[wave][e] = acc[e];
  }
  __syncthreads();
  if (tid == 0) {
    float loss = 0.f;
#pragma unroll
    for (int e = 0; e < EE; ++e) {
      const float m = (sm[0][e] + sm[1][e] + sm[2][e] + sm[3][e]) * (1.f / TT);
      tail[1 + e] = m;
      loss += m * m;
    }
    tail[0] = (float)EE * loss;
  }
}

// ---------------- routing: compacted token lists (pad to 256) + tile tables ----------------
__global__ __launch_bounds__(512) void route_kernel(
    const int2* __restrict__ topk, const float* __restrict__ combine,
    int* __restrict__ tok_list, float* __restrict__ wt_list,
    int* __restrict__ tab256, int* __restrict__ tab128) {
  const int lane = threadIdx.x & 63;
  const int e = threadIdx.x >> 6;  // one wave per expert
  __shared__ int cnts[EE], offs[EE];
  int cnt = 0;
  for (int i = 0; i < TT / 64; ++i) {
    const int2 k2 = topk[i * 64 + lane];
    cnt += __popcll(__ballot(k2.x == e || k2.y == e));
  }
  if (lane == 0) cnts[e] = cnt;
  __syncthreads();
  if (threadIdx.x == 0) {
    int off = 0, n256 = 0, n128 = 0;
    for (int f = 0; f < EE; ++f) {
      offs[f] = off;
      const int pc = (cnts[f] + 255) & ~255;
      for (int j = 0; j < (pc >> 8); ++j) {
        tab256[2 * n256] = f; tab256[2 * n256 + 1] = off + 256 * j; ++n256;
      }
      for (int j = 0; j < (pc >> 7); ++j) {
        tab128[2 * n128] = f; tab128[2 * n128 + 1] = off + 128 * j; ++n128;
      }
      off += pc;
    }
    for (; n256 < MT256; ++n256) { tab256[2 * n256] = -1; tab256[2 * n256 + 1] = 0; }
    for (; n128 < MT128; ++n128) { tab128[2 * n128] = -1; tab128[2 * n128 + 1] = 0; }
  }
  __syncthreads();
  int pos = offs[e];
  for (int i = 0; i < TT / 64; ++i) {
    const int t = i * 64 + lane;
    const int2 k2 = topk[t];
    const bool sel = (k2.x == e || k2.y == e);
    const unsigned long long m = __ballot(sel);
    if (sel) {
      const int p = pos + __popcll(m & ((1ull << lane) - 1ull));
      tok_list[p] = t;
      wt_list[p] = combine[(size_t)t * EE + e];
    }
    pos += __popcll(m);
  }
  const int pc = (cnt + 255) & ~255;  // pad slots: token 0, weight 0
  for (int s = cnt + lane; s < pc; s += 64) {
    tok_list[offs[e] + s] = 0;
    wt_list[offs[e] + s] = 0.f;
  }
}

// ---------------- gather x rows (f32 -> bf16) into contiguous padded buffer ----------------
__global__ __launch_bounds__(256) void gather_x(
    const float* __restrict__ x, const int* __restrict__ tok_list,
    const int* __restrict__ tab256, unsigned short* __restrict__ xg) {
  const int e = tab256[2 * blockIdx.x];
  if (e < 0) return;
  const int row0 = tab256[2 * blockIdx.x + 1] + blockIdx.y * 16;
  const int tid = threadIdx.x;
#pragma unroll
  for (int i = 0; i < 16; ++i) {
    const int row = row0 + i;
    const int tok = tok_list[row];
    const f32x4 v = *(const f32x4*)(x + (size_t)tok * DD + tid * 4);
    unsigned short b[4] = {f2bf(v[0]), f2bf(v[1]), f2bf(v[2]), f2bf(v[3])};
    *(short4v*)(xg + (size_t)row * DD + tid * 4) = *(const short4v*)b;
  }
}

// ---------------- grouped GEMM: m97 structure. 128x128 tile, 4 waves, BK=64, ----------------
// single 32KB LDS buffer, global_load_lds staging, 3 blocks/CU TLP hides the barrier drain.
// MODE 0: A=xg [row][DD], B=wguT interleaved [e][2H][DD]; epilogue silu(g)*u -> act bf16
// MODE 1: A=act [row][HH], B=wdT [e][DD][HH]; epilogue atomic scatter * combine wt
// LDS rows 128B; swizzle: phys 16B-chunk = logical ^ (row&7), applied on gll SOURCE and read.
// Staging: 256 threads x 16B = 4096B per pass; 4 passes per 16KB tile (dest q*4096+srel).
template <int MODE>
__global__ __launch_bounds__(256, 3) void gemm128(
    const unsigned short* __restrict__ Ab, const unsigned short* __restrict__ Bb,
    const int* __restrict__ tab, const int* __restrict__ tok_list,
    const float* __restrict__ wt_list, unsigned short* __restrict__ act,
    float* __restrict__ out) {
  constexpr int K   = (MODE == 0) ? DD : HH;     // 1024 / 1792
  constexpr int NBR = (MODE == 0) ? 2 * HH : DD; // B rows per expert
  constexpr int NNT = NBR / 128;                 // 28 / 8
  __shared__ unsigned short As[128 * 64];
  __shared__ unsigned short Bs[128 * 64];

  const int nwg = gridDim.x;  // %8==0 for both modes
  const int wgid = (blockIdx.x & 7) * (nwg >> 3) + (blockIdx.x >> 3);
  const int mt = wgid / NNT, nt = wgid % NNT;
  const int e = tab[2 * mt];
  if (e < 0) return;
  const int row0 = tab[2 * mt + 1];
  const int n0 = nt * 128;

  const int tid = threadIdx.x, lane = tid & 63, wave = tid >> 6;
  const int wm = (wave >> 1) * 64, wn = (wave & 1) * 64;
  const int fr = lane & 15, hi = lane >> 4;

  const unsigned short* At = Ab + (size_t)row0 * K;
  const unsigned short* Bt = Bb + ((size_t)e * NBR + n0) * K;

  // per-thread staging geometry: pass q covers LDS bytes [q*4096, q*4096+4096)
  const int srel = tid * 16;                 // [0, 4096)
  const int srow0 = srel >> 7;               // [0, 32); pass q handles rows q*32+srow0
  const int sch = (srel >> 4) & 7;           // 16B chunk within 128B row

  f32x4 acc[4][4];
#pragma unroll
  for (int i = 0; i < 4; ++i)
#pragma unroll
    for (int j = 0; j < 4; ++j) acc[i][j] = (f32x4){0.f, 0.f, 0.f, 0.f};

  for (int k0 = 0; k0 < K; k0 += 64) {
#pragma unroll
    for (int q = 0; q < 4; ++q) {  // A tile: 16KB
      const int row = q * 32 + srow0;
      gll16(At + (size_t)row * K + k0 + ((sch ^ (row & 7)) << 3),
            (const char*)As + q * 4096 + srel);
    }
#pragma unroll
    for (int q = 0; q < 4; ++q) {  // B tile: 16KB
      const int row = q * 32 + srow0;
      gll16(Bt + (size_t)row * K + k0 + ((sch ^ (row & 7)) << 3),
            (const char*)Bs + q * 4096 + srel);
    }
    __syncthreads();  // compiler drains vmcnt+lgkmcnt
#pragma unroll
    for (int kc = 0; kc < 2; ++kc) {
      short8 a[4], b[4];
#pragma unroll
      for (int i = 0; i < 4; ++i) {
        const int row = wm + i * 16 + fr;
        const int byt = (row * 128 + kc * 64 + hi * 16) ^ ((row & 7) << 4);
        a[i] = *(const short8*)((const char*)As + byt);
      }
#pragma unroll
      for (int j = 0; j < 4; ++j) {
        const int row = wn + j * 16 + fr;
        const int byt = (row * 128 + kc * 64 + hi * 16) ^ ((row & 7) << 4);
        b[j] = *(const short8*)((const char*)Bs + byt);
      }
#pragma unroll
      for (int i = 0; i < 4; ++i)
#pragma unroll
        for (int j = 0; j < 4; ++j)
          acc[i][j] = __builtin_amdgcn_mfma_f32_16x16x32_bf16(a[i], b[j], acc[i][j], 0, 0, 0);
    }
    __syncthreads();
  }

  const int r4 = hi * 4;
  if constexpr (MODE == 0) {
#pragma unroll
    for (int i = 0; i < 4; ++i)
#pragma unroll
      for (int r = 0; r < 4; ++r) {
        const int row = row0 + wm + i * 16 + r4 + r;
#pragma unroll
        for (int jj = 0; jj < 2; ++jj) {
          const float g = acc[i][2 * jj][r], u = acc[i][2 * jj + 1][r];
          const int nb = n0 + wn + jj * 32;
          const int h = ((nb >> 5) << 4) + fr;   // de-interleave to real H col
          act[(size_t)row * HH + h] = f2bf((g / (1.f + expf(-g))) * u);
        }
      }
  } else {
#pragma unroll
    for (int i = 0; i < 4; ++i)
#pragma unroll
      for (int r = 0; r < 4; ++r) {
        const int rl = row0 + wm + i * 16 + r4 + r;
        const int tok = tok_list[rl];
        const float wt = wt_list[rl];
        if (wt != 0.f) {
#pragma unroll
          for (int j = 0; j < 4; ++j)
            unsafeAtomicAdd(&out[(size_t)tok * DD + n0 + wn + j * 16 + fr],
                            acc[i][j][r] * wt);
        }
      }
  }
}

extern "C" void kernel_launch(void* const* d_in, const int* in_sizes, int n_in,
                              void* d_out, int out_size, void* d_ws, size_t ws_size,
                              hipStream_t stream) {
  const float* x      = (const float*)d_in[0];
  const float* gw     = (const float*)d_in[1];
  const float* w_gate = (const float*)d_in[2];
  const float* w_up   = (const float*)d_in[3];
  const float* w_down = (const float*)d_in[4];
  float* out = (float*)d_out;
  float* tail = out + (size_t)TT * DD;  // [loss, mean_probs x 8]

  char* w = (char*)d_ws;
  size_t o = 0;
  auto carve = [&](size_t bytes) { char* p = w + o; o += (bytes + 255) & ~255ull; return p; };
  unsigned short* wguT = (unsigned short*)carve((size_t)EE * 2 * HH * DD * 2);  // interleaved G/U
  unsigned short* wdT  = (unsigned short*)carve((size_t)EE * DD * HH * 2);
  unsigned short* xg   = (unsigned short*)carve((size_t)MP * DD * 2);
  unsigned short* act  = (unsigned short*)carve((size_t)MP * HH * 2);
  float* combine = (float*)carve((size_t)TT * EE * 4);
  float* probs   = (float*)carve((size_t)TT * EE * 4);
  int2* topk     = (int2*)carve((size_t)TT * 8);
  int* tok_list  = (int*)carve((size_t)MP * 4);
  float* wt_list = (float*)carve((size_t)MP * 4);
  int* tab256    = (int*)carve((size_t)MT256 * 8);
  int* tab128    = (int*)carve((size_t)MT128 * 8);

  hipMemsetAsync(out, 0, (size_t)TT * DD * sizeof(float), stream);

  transpose_convert<<<dim3(DD / 64, HH / 64, EE), 256, 0, stream>>>(w_gate, wguT, DD, HH, 1, 0);
  transpose_convert<<<dim3(DD / 64, HH / 64, EE), 256, 0, stream>>>(w_up,   wguT, DD, HH, 1, 1);
  transpose_convert<<<dim3(HH / 64, DD / 64, EE), 256, 0, stream>>>(w_down, wdT,  HH, DD, 0, 0);

  gate_kernel<<<TT / 4, 256, 0, stream>>>(x, gw, combine, probs, topk);
  reduce_kernel<<<1, 256, 0, stream>>>(probs, tail);
  route_kernel<<<1, 512, 0, stream>>>(topk, combine, tok_list, wt_list, tab256, tab128);
  gather_x<<<dim3(MT256, 16), 256, 0, stream>>>(x, tok_list, tab256, xg);

  gemm128<0><<<MT128 * 28, 256, 0, stream>>>(xg, wguT, tab128, nullptr, nullptr, act, nullptr);
  gemm128<1><<<MT128 * 8, 256, 0, stream>>>(act, wdT, tab128, tok_list, wt_list, nullptr, out);
}